// Round 4
// baseline (267.453 us; speedup 1.0000x reference)
//
#include <hip/hip_runtime.h>
#include <hip/hip_bf16.h>
#include <math.h>

#define BB 2
#define SS 1024
#define DD 1024
#define HH 16
#define HD 64
#define BH (BB*HH)

typedef __attribute__((ext_vector_type(8))) short short8_t;
typedef __attribute__((ext_vector_type(4))) float f32x4;

#if __has_builtin(__builtin_amdgcn_exp2f)
#define EXP2(x) __builtin_amdgcn_exp2f(x)
#else
#define EXP2(x) exp2f(x)
#endif

__device__ __forceinline__ ushort f2bf(float f) {
    union { float f; unsigned u; } a; a.f = f;
    unsigned u = a.u;
    u += 0x7FFFu + ((u >> 16) & 1u);   // RNE
    return (ushort)(u >> 16);
}
__device__ __forceinline__ float bf2f(ushort b) {
    union { unsigned u; float f; } a; a.u = ((unsigned)b) << 16;
    return a.f;
}
// packed f32x2 -> bf16x2 (RNE), low = a
__device__ __forceinline__ unsigned pkbf(float a, float b) {
    unsigned r;
    asm("v_cvt_pk_bf16_f32 %0, %1, %2" : "=v"(r) : "v"(a), "v"(b));
    return r;
}

// ---------------- fp32 -> bf16 conversion, all 5 tensors in one launch ----------------
__global__ __launch_bounds__(256) void cvt_all_kernel(
    const float* __restrict__ x,  const float* __restrict__ wq,
    const float* __restrict__ wk, const float* __restrict__ wv,
    const float* __restrict__ wo,
    ushort* __restrict__ xb,  ushort* __restrict__ wqb, ushort* __restrict__ wkb,
    ushort* __restrict__ wvb, ushort* __restrict__ wob)
{
    int bid = blockIdx.x;
    const float* src; ushort* dst; int off;
    if (bid < 2048) { src = x; dst = xb; off = bid; }
    else {
        int seg = (bid - 2048) >> 10;
        off = (bid - 2048) & 1023;
        if (seg == 0)      { src = wq; dst = wqb; }
        else if (seg == 1) { src = wk; dst = wkb; }
        else if (seg == 2) { src = wv; dst = wvb; }
        else               { src = wo; dst = wob; }
    }
    int i = (off * 256 + threadIdx.x) * 4;
    float4 v = *reinterpret_cast<const float4*>(src + i);
    ushort4 o;
    o.x = f2bf(v.x); o.y = f2bf(v.y); o.z = f2bf(v.z); o.w = f2bf(v.w);
    *reinterpret_cast<ushort4*>(dst + i) = o;
}

// ---------------- bf16 GEMM (m97 structure): C = A[M,K]*B[N,K]^T, global_load_lds ----------------
template<int BM, int OUT_F32>
__device__ __forceinline__ void gemm_body(
    const ushort* __restrict__ A, const ushort* __restrict__ Bm,
    const float* __restrict__ bias, void* __restrict__ Cout,
    int N, int K, float scale)
{
    constexpr int BK = 32;
    __shared__ ushort lsa[BM * BK];
    __shared__ ushort lsb[128 * BK];
    const int tid  = threadIdx.x;
    const int lane = tid & 63;
    const int wave = tid >> 6;
    constexpr int RI = BM / 32;
    const int wrow = (wave >> 1) * (BM / 2);
    const int wcol = (wave & 1) * 64;
    const int tileM = blockIdx.y * BM;
    const int tileN = blockIdx.x * 128;
    const int fr  = lane & 15;
    const int fks = (lane >> 4) * 8;
    const int l4  = lane >> 2;        // row within 16-row chunk
    const int lm4 = lane & 3;         // 16B slot within 64B row
    f32x4 acc[RI][4] = {};

    for (int kb = 0; kb < K; kb += BK) {
        __syncthreads();
        #pragma unroll
        for (int i = 0; i < BM / 64; ++i) {
            int chunk = wave * (BM / 64) + i;
            const ushort* g = A + (size_t)(tileM + chunk * 16 + l4) * K + kb + lm4 * 8;
            __builtin_amdgcn_global_load_lds(
                (const __attribute__((address_space(1))) unsigned*)g,
                (__attribute__((address_space(3))) unsigned*)&lsa[chunk * 512], 16, 0, 0);
        }
        #pragma unroll
        for (int i = 0; i < 2; ++i) {
            int chunk = wave * 2 + i;
            const ushort* g = Bm + (size_t)(tileN + chunk * 16 + l4) * K + kb + lm4 * 8;
            __builtin_amdgcn_global_load_lds(
                (const __attribute__((address_space(1))) unsigned*)g,
                (__attribute__((address_space(3))) unsigned*)&lsb[chunk * 512], 16, 0, 0);
        }
        __syncthreads();
        short8_t af[RI], bfg[4];
        #pragma unroll
        for (int r = 0; r < RI; ++r)
            af[r] = *reinterpret_cast<const short8_t*>(&lsa[(wrow + r * 16 + fr) * BK + fks]);
        #pragma unroll
        for (int c = 0; c < 4; ++c)
            bfg[c] = *reinterpret_cast<const short8_t*>(&lsb[(wcol + c * 16 + fr) * BK + fks]);
        #pragma unroll
        for (int r = 0; r < RI; ++r)
            #pragma unroll
            for (int c = 0; c < 4; ++c)
                acc[r][c] = __builtin_amdgcn_mfma_f32_16x16x32_bf16(af[r], bfg[c], acc[r][c], 0, 0, 0);
    }

    const int rr = (lane >> 4) * 4;
    #pragma unroll
    for (int r = 0; r < RI; ++r) {
        #pragma unroll
        for (int c = 0; c < 4; ++c) {
            int n = tileN + wcol + c * 16 + fr;
            float bv = bias[n];
            #pragma unroll
            for (int q = 0; q < 4; ++q) {
                int m = tileM + wrow + r * 16 + rr + q;
                float v = (acc[r][c][q] + bv) * scale;
                if (OUT_F32) ((float*)Cout)[(size_t)m * N + n] = v;
                else         ((ushort*)Cout)[(size_t)m * N + n] = f2bf(v);
            }
        }
    }
}

__global__ __launch_bounds__(256) void gemm_qkv_kernel(
    const ushort* __restrict__ xb,
    const ushort* __restrict__ wq, const ushort* __restrict__ wk, const ushort* __restrict__ wv,
    const float* __restrict__ bq, const float* __restrict__ bk, const float* __restrict__ bv,
    ushort* __restrict__ Qb, ushort* __restrict__ Kb, ushort* __restrict__ Vb, float qscale)
{
    const ushort* Bm; const float* bias; ushort* out; float sc;
    if (blockIdx.z == 0)      { Bm = wq; bias = bq; out = Qb; sc = qscale; }
    else if (blockIdx.z == 1) { Bm = wk; bias = bk; out = Kb; sc = 1.0f; }
    else                      { Bm = wv; bias = bv; out = Vb; sc = 1.0f; }
    gemm_body<128, 0>(xb, Bm, bias, out, DD, DD, sc);
}

__global__ __launch_bounds__(256) void gemm_out_kernel(
    const ushort* __restrict__ ctxb, const ushort* __restrict__ wo,
    const float* __restrict__ bo, float* __restrict__ out)
{
    gemm_body<64, 1>(ctxb, wo, bo, out, DD, DD, 1.0f);
}

// ---------------- z table: zt[bh,j] = 0.025*log2e * pf[h] * sum_d K[b,j,h*64+d] ----------------
__global__ __launch_bounds__(256) void ztab_kernel(const ushort* __restrict__ Kb,
                                                   const float* __restrict__ pf,
                                                   float* __restrict__ zt, float azc) {
    int idx = blockIdx.x * blockDim.x + threadIdx.x;  // [0, BH*SS)
    int j  = idx & (SS - 1);
    int bh = idx >> 10;
    int b = bh >> 4, h = bh & 15;
    const ushort* kr = Kb + (size_t)(b * SS + j) * DD + h * HD;
    float s = 0.f;
    #pragma unroll
    for (int c = 0; c < HD; c += 8) {
        short8_t v = *reinterpret_cast<const short8_t*>(kr + c);
        #pragma unroll
        for (int e = 0; e < 8; ++e) s += bf2f((ushort)v[e]);
    }
    zt[idx] = azc * pf[h] * s;
}

// ---------------- V transpose: Vt[b,h,d,j] = V[b,j,h*64+d] ----------------
__global__ __launch_bounds__(256) void transpose_v_kernel(const ushort* __restrict__ Vb,
                                                          ushort* __restrict__ Vt) {
    __shared__ ushort t[64][72];
    int bh = blockIdx.x; int b = bh >> 4, h = bh & 15;
    int j0 = blockIdx.y * 64;
    #pragma unroll
    for (int s = 0; s < 2; ++s) {
        int ch = threadIdx.x + s * 256;
        int row = ch >> 3, c = (ch & 7) * 8;
        *reinterpret_cast<short8_t*>(&t[row][c]) =
            *reinterpret_cast<const short8_t*>(Vb + (size_t)(b * SS + j0 + row) * DD + h * HD + c);
    }
    __syncthreads();
    #pragma unroll
    for (int s = 0; s < 2; ++s) {
        int ch = threadIdx.x + s * 256;
        int drow = ch >> 3, c = (ch & 7) * 8;
        short8_t v;
        #pragma unroll
        for (int e = 0; e < 8; ++e) v[e] = (short)t[c + e][drow];
        *reinterpret_cast<short8_t*>(Vt + (size_t)(bh * HD + drow) * SS + j0 + c) = v;
    }
}

// ---------------- single-pass resonance attention (software-pipelined) ----------------
// Q pre-scaled: QK^T gives S' = 0.025*log2e*S.  z table in LDS.
// u = exp2(S'+z), w = exp2(S'-z):  p0=u2w2, p1=u^5, p2=u3w3, p3=w^7.
// it-loop fully unrolled; K frags for tile it+1 prefetched before exp/PV of tile it.
__global__ __launch_bounds__(256, 3) void attn_kernel(
    const ushort* __restrict__ Qb, const ushort* __restrict__ Kb,
    const ushort* __restrict__ Vt, const float* __restrict__ zt,
    ushort* __restrict__ ctxb)
{
    __shared__ float sbuf[4][16][68];   // per-wave score transpose; reused as ctx partials
    __shared__ float zbuf[4][256];      // per-wave z slice
    __shared__ float lbuf[4][4][16];    // [wave][t][row]
    const int wg  = blockIdx.x;
    const int swz = (wg & 7) * 256 + (wg >> 3);   // XCD swizzle (2048 % 8 == 0)
    const int bh  = swz >> 6;
    const int qt  = swz & 63;
    const int b = bh >> 4, h = bh & 15;
    const int wave = threadIdx.x >> 6;
    const int lane = threadIdx.x & 63;
    const int fr = lane & 15;
    const int g  = lane >> 4;
    const int fk = g * 8;

    const float wt[4] = {0.008f, 0.032f, 0.16f, 0.8f};   // momentum-collapsed weights

    // stage this wave's z slice (wave-private region, same-wave DS in-order)
    {
        float4 zv4 = *reinterpret_cast<const float4*>(zt + bh * SS + wave * 256 + lane * 4);
        *reinterpret_cast<float4*>(&zbuf[wave][lane * 4]) = zv4;
    }

    // Q A-fragments (pre-scaled), 16 rows per block
    const ushort* qbase = Qb + (size_t)(b * SS + qt * 16 + fr) * DD + h * HD;
    const short8_t aq0 = *reinterpret_cast<const short8_t*>(qbase + fk);
    const short8_t aq1 = *reinterpret_cast<const short8_t*>(qbase + 32 + fk);

    f32x4 cacc[4][4] = {};   // [t][n2]  PV accumulators
    float l[4] = {0.f, 0.f, 0.f, 0.f};

    const ushort* kcol = Kb + (size_t)b * SS * DD + h * HD + (size_t)(wave * 256 + fr) * DD;
    const ushort* vwb  = Vt + (size_t)bh * HD * SS + wave * 256;

    // ---- prologue: K frags + QK^T for tile 0 ----
    short8_t nk0[4], nk1[4];
    #pragma unroll
    for (int n = 0; n < 4; ++n) {
        const ushort* kb = kcol + (size_t)(n * 16) * DD;
        nk0[n] = *reinterpret_cast<const short8_t*>(kb + fk);
        nk1[n] = *reinterpret_cast<const short8_t*>(kb + 32 + fk);
    }
    f32x4 accn[4];
    #pragma unroll
    for (int n = 0; n < 4; ++n) {
        f32x4 z4 = {0.f, 0.f, 0.f, 0.f};
        z4 = __builtin_amdgcn_mfma_f32_16x16x32_bf16(aq0, nk0[n], z4, 0, 0, 0);
        z4 = __builtin_amdgcn_mfma_f32_16x16x32_bf16(aq1, nk1[n], z4, 0, 0, 0);
        accn[n] = z4;
    }

    union FragU { short8_t s; unsigned u[4]; };

    #pragma unroll
    for (int it = 0; it < 4; ++it) {
        const int kl = it * 64;

        // ---- current scores -> LDS (C-layout), read back in A-frag layout ----
        #pragma unroll
        for (int n = 0; n < 4; ++n)
            #pragma unroll
            for (int r = 0; r < 4; ++r)
                sbuf[wave][g * 4 + r][n * 16 + fr] = accn[n][r];

        f32x4 sa0 = *reinterpret_cast<f32x4*>(&sbuf[wave][fr][fk]);
        f32x4 sa1 = *reinterpret_cast<f32x4*>(&sbuf[wave][fr][fk + 4]);
        f32x4 sa2 = *reinterpret_cast<f32x4*>(&sbuf[wave][fr][32 + fk]);
        f32x4 sa3 = *reinterpret_cast<f32x4*>(&sbuf[wave][fr][36 + fk]);

        // ---- prefetch K fragments for tile it+1 (issued ~400cyc before use) ----
        if (it < 3) {
            #pragma unroll
            for (int n = 0; n < 4; ++n) {
                const ushort* kb = kcol + (size_t)(kl + 64 + n * 16) * DD;
                nk0[n] = *reinterpret_cast<const short8_t*>(kb + fk);
                nk1[n] = *reinterpret_cast<const short8_t*>(kb + 32 + fk);
            }
        }

        // ---- half 0: exp/powers/pack + PV over k-slice [k0, k0+32) ----
        {
            f32x4 zv0 = *reinterpret_cast<f32x4*>(&zbuf[wave][kl + fk]);
            f32x4 zv1 = *reinterpret_cast<f32x4*>(&zbuf[wave][kl + fk + 4]);
            float p0[8], p1[8], p2[8], p3[8];
            #pragma unroll
            for (int e = 0; e < 8; ++e) {
                float s  = (e < 4) ? sa0[e] : sa1[e - 4];
                float zz = (e < 4) ? zv0[e] : zv1[e - 4];
                float u = EXP2(s + zz);
                float w = EXP2(s - zz);
                float u2 = u * u, w2 = w * w;
                float q0 = u2 * w2;
                float uw = u * w;
                float q2 = q0 * uw;
                float q1 = u2 * u2 * u;
                float w4 = w2 * w2;
                float q3 = w4 * w2 * w;
                p0[e] = q0; p1[e] = q1; p2[e] = q2; p3[e] = q3;
                l[0] += q0; l[1] += q1; l[2] += q2; l[3] += q3;
            }
            FragU pa[4];
            #pragma unroll
            for (int i2 = 0; i2 < 4; ++i2) {
                pa[0].u[i2] = pkbf(p0[2*i2], p0[2*i2+1]);
                pa[1].u[i2] = pkbf(p1[2*i2], p1[2*i2+1]);
                pa[2].u[i2] = pkbf(p2[2*i2], p2[2*i2+1]);
                pa[3].u[i2] = pkbf(p3[2*i2], p3[2*i2+1]);
            }
            #pragma unroll
            for (int n2 = 0; n2 < 4; ++n2) {
                short8_t v = *reinterpret_cast<const short8_t*>(
                    vwb + (size_t)(n2 * 16 + fr) * SS + kl + fk);
                #pragma unroll
                for (int t = 0; t < 4; ++t)
                    cacc[t][n2] = __builtin_amdgcn_mfma_f32_16x16x32_bf16(pa[t].s, v, cacc[t][n2], 0, 0, 0);
            }
        }

        // ---- QK^T for tile it+1 (prefetched K should have landed; MFMA pipe idle) ----
        if (it < 3) {
            #pragma unroll
            for (int n = 0; n < 4; ++n) {
                f32x4 z4 = {0.f, 0.f, 0.f, 0.f};
                z4 = __builtin_amdgcn_mfma_f32_16x16x32_bf16(aq0, nk0[n], z4, 0, 0, 0);
                z4 = __builtin_amdgcn_mfma_f32_16x16x32_bf16(aq1, nk1[n], z4, 0, 0, 0);
                accn[n] = z4;
            }
        }

        // ---- half 1: exp/powers/pack + PV over k-slice [k0+32, k0+64) ----
        {
            f32x4 zv2 = *reinterpret_cast<f32x4*>(&zbuf[wave][kl + 32 + fk]);
            f32x4 zv3 = *reinterpret_cast<f32x4*>(&zbuf[wave][kl + 36 + fk]);
            float p0[8], p1[8], p2[8], p3[8];
            #pragma unroll
            for (int e = 0; e < 8; ++e) {
                float s  = (e < 4) ? sa2[e] : sa3[e - 4];
                float zz = (e < 4) ? zv2[e] : zv3[e - 4];
                float u = EXP2(s + zz);
                float w = EXP2(s - zz);
                float u2 = u * u, w2 = w * w;
                float q0 = u2 * w2;
                float uw = u * w;
                float q2 = q0 * uw;
                float q1 = u2 * u2 * u;
                float w4 = w2 * w2;
                float q3 = w4 * w2 * w;
                p0[e] = q0; p1[e] = q1; p2[e] = q2; p3[e] = q3;
                l[0] += q0; l[1] += q1; l[2] += q2; l[3] += q3;
            }
            FragU pa[4];
            #pragma unroll
            for (int i2 = 0; i2 < 4; ++i2) {
                pa[0].u[i2] = pkbf(p0[2*i2], p0[2*i2+1]);
                pa[1].u[i2] = pkbf(p1[2*i2], p1[2*i2+1]);
                pa[2].u[i2] = pkbf(p2[2*i2], p2[2*i2+1]);
                pa[3].u[i2] = pkbf(p3[2*i2], p3[2*i2+1]);
            }
            #pragma unroll
            for (int n2 = 0; n2 < 4; ++n2) {
                short8_t v = *reinterpret_cast<const short8_t*>(
                    vwb + (size_t)(n2 * 16 + fr) * SS + kl + 32 + fk);
                #pragma unroll
                for (int t = 0; t < 4; ++t)
                    cacc[t][n2] = __builtin_amdgcn_mfma_f32_16x16x32_bf16(pa[t].s, v, cacc[t][n2], 0, 0, 0);
            }
        }
    }

    // ---- epilogue: reduce l (l[t] is partial for row fr) ----
    #pragma unroll
    for (int t = 0; t < 4; ++t) {
        float lt = l[t];
        lt += __shfl_xor(lt, 16);
        lt += __shfl_xor(lt, 32);
        if (lane < 16) lbuf[wave][t][lane] = lt;
    }
    __syncthreads();
    float wlf[4];
    #pragma unroll
    for (int t = 0; t < 4; ++t) {
        float s = lbuf[0][t][fr] + lbuf[1][t][fr] + lbuf[2][t][fr] + lbuf[3][t][fr];
        wlf[t] = wt[t] / s;
    }
    // per-lane C-layout rows are g*4+q; fetch wl for those rows
    float wls[4][4];
    #pragma unroll
    for (int t = 0; t < 4; ++t)
        #pragma unroll
        for (int q = 0; q < 4; ++q)
            wls[t][q] = __shfl(wlf[t], g * 4 + q);

    // combine t in-register, write per-wave partial ctx into (reused) sbuf
    #pragma unroll
    for (int n2 = 0; n2 < 4; ++n2) {
        #pragma unroll
        for (int q = 0; q < 4; ++q) {
            float v = wls[0][q] * cacc[0][n2][q] + wls[1][q] * cacc[1][n2][q]
                    + wls[2][q] * cacc[2][n2][q] + wls[3][q] * cacc[3][n2][q];
            sbuf[wave][g * 4 + q][n2 * 16 + fr] = v;
        }
    }
    __syncthreads();

    // final: sum 4 wave partials, write bf16 ctx
    const int row = threadIdx.x >> 4;
    const int d0  = (threadIdx.x & 15) * 4;
    float4 s0 = *reinterpret_cast<float4*>(&sbuf[0][row][d0]);
    float4 s1 = *reinterpret_cast<float4*>(&sbuf[1][row][d0]);
    float4 s2 = *reinterpret_cast<float4*>(&sbuf[2][row][d0]);
    float4 s3 = *reinterpret_cast<float4*>(&sbuf[3][row][d0]);
    float ox = s0.x + s1.x + s2.x + s3.x;
    float oy = s0.y + s1.y + s2.y + s3.y;
    float oz = s0.z + s1.z + s2.z + s3.z;
    float ow = s0.w + s1.w + s2.w + s3.w;
    uint2 o;
    o.x = pkbf(ox, oy);
    o.y = pkbf(oz, ow);
    size_t off = (size_t)(b * SS + qt * 16 + row) * DD + h * HD + d0;
    *reinterpret_cast<uint2*>(ctxb + off) = o;
}

// ---------------- launch ----------------
extern "C" void kernel_launch(void* const* d_in, const int* in_sizes, int n_in,
                              void* d_out, int out_size, void* d_ws, size_t ws_size,
                              hipStream_t stream) {
    const float* x  = (const float*)d_in[0];
    const float* Wq = (const float*)d_in[1];
    const float* bq = (const float*)d_in[2];
    const float* Wk = (const float*)d_in[3];
    const float* bk = (const float*)d_in[4];
    const float* Wv = (const float*)d_in[5];
    const float* bv = (const float*)d_in[6];
    const float* Wo = (const float*)d_in[7];
    const float* bo = (const float*)d_in[8];
    // d_in[9] resonance_bias: per-head row-constant -> cancels in softmax
    const float* pf = (const float*)d_in[10];

    // workspace layout (~32.2 MB)
    ushort* xb   = (ushort*)d_ws;
    ushort* wqb  = xb  + (size_t)2 * 1024 * 1024;
    ushort* wkb  = wqb + (size_t)1024 * 1024;
    ushort* wvb  = wkb + (size_t)1024 * 1024;
    ushort* wob  = wvb + (size_t)1024 * 1024;
    ushort* Qb   = wob + (size_t)1024 * 1024;
    ushort* Kb   = Qb  + (size_t)2 * 1024 * 1024;
    ushort* Vb   = Kb  + (size_t)2 * 1024 * 1024;
    ushort* Vt   = Vb  + (size_t)2 * 1024 * 1024;
    ushort* ctxb = Vt  + (size_t)2 * 1024 * 1024;
    float*  ztp  = (float*)(ctxb + (size_t)2 * 1024 * 1024);

    const double LOG2E = 1.44269504088896340736;
    float qscale = (float)(0.025 * LOG2E);     // Q pre-scale: S' = 0.025*log2e*S
    float azc    = (float)(0.025 * LOG2E);     // z = 0.025*log2e*pf*rk

    cvt_all_kernel<<<6144, 256, 0, stream>>>(x, Wq, Wk, Wv, Wo, xb, wqb, wkb, wvb, wob);

    gemm_qkv_kernel<<<dim3(8, 16, 3), 256, 0, stream>>>(xb, wqb, wkb, wvb, bq, bk, bv,
                                                        Qb, Kb, Vb, qscale);

    ztab_kernel<<<BH * SS / 256, 256, 0, stream>>>(Kb, pf, ztp, azc);
    transpose_v_kernel<<<dim3(BH, SS / 64), 256, 0, stream>>>(Vb, Vt);

    attn_kernel<<<2048, 256, 0, stream>>>(Qb, Kb, Vt, ztp, ctxb);

    gemm_out_kernel<<<dim3(8, 32), 256, 0, stream>>>(ctxb, wob, bo, (float*)d_out);
}

// Round 5
// 129.890 us; speedup vs baseline: 2.0591x; 2.0591x over previous
//
#include <hip/hip_runtime.h>
#include <hip/hip_bf16.h>
#include <math.h>

#define BB 2
#define SS 1024
#define DD 1024
#define HH 16
#define HD 64
#define BH (BB*HH)

typedef __attribute__((ext_vector_type(8))) short short8_t;
typedef __attribute__((ext_vector_type(4))) float f32x4;

#if __has_builtin(__builtin_amdgcn_exp2f)
#define EXP2(x) __builtin_amdgcn_exp2f(x)
#else
#define EXP2(x) exp2f(x)
#endif

__device__ __forceinline__ ushort f2bf(float f) {
    union { float f; unsigned u; } a; a.f = f;
    unsigned u = a.u;
    u += 0x7FFFu + ((u >> 16) & 1u);   // RNE
    return (ushort)(u >> 16);
}
__device__ __forceinline__ float bf2f(ushort b) {
    union { unsigned u; float f; } a; a.u = ((unsigned)b) << 16;
    return a.f;
}
// packed f32x2 -> bf16x2 (RNE), low = a
__device__ __forceinline__ unsigned pkbf(float a, float b) {
    unsigned r;
    asm("v_cvt_pk_bf16_f32 %0, %1, %2" : "=v"(r) : "v"(a), "v"(b));
    return r;
}

// ---------------- fp32 -> bf16 conversion, all 5 tensors in one launch ----------------
__global__ __launch_bounds__(256) void cvt_all_kernel(
    const float* __restrict__ x,  const float* __restrict__ wq,
    const float* __restrict__ wk, const float* __restrict__ wv,
    const float* __restrict__ wo,
    ushort* __restrict__ xb,  ushort* __restrict__ wqb, ushort* __restrict__ wkb,
    ushort* __restrict__ wvb, ushort* __restrict__ wob)
{
    int bid = blockIdx.x;
    const float* src; ushort* dst; int off;
    if (bid < 2048) { src = x; dst = xb; off = bid; }
    else {
        int seg = (bid - 2048) >> 10;
        off = (bid - 2048) & 1023;
        if (seg == 0)      { src = wq; dst = wqb; }
        else if (seg == 1) { src = wk; dst = wkb; }
        else if (seg == 2) { src = wv; dst = wvb; }
        else               { src = wo; dst = wob; }
    }
    int i = (off * 256 + threadIdx.x) * 4;
    float4 v = *reinterpret_cast<const float4*>(src + i);
    ushort4 o;
    o.x = f2bf(v.x); o.y = f2bf(v.y); o.z = f2bf(v.z); o.w = f2bf(v.w);
    *reinterpret_cast<ushort4*>(dst + i) = o;
}

// ---------------- bf16 GEMM (m97 structure): C = A[M,K]*B[N,K]^T, global_load_lds ----------------
template<int BM, int OUT_F32>
__device__ __forceinline__ void gemm_body(
    const ushort* __restrict__ A, const ushort* __restrict__ Bm,
    const float* __restrict__ bias, void* __restrict__ Cout,
    int N, int K, float scale)
{
    constexpr int BK = 32;
    __shared__ ushort lsa[BM * BK];
    __shared__ ushort lsb[128 * BK];
    const int tid  = threadIdx.x;
    const int lane = tid & 63;
    const int wave = tid >> 6;
    constexpr int RI = BM / 32;
    const int wrow = (wave >> 1) * (BM / 2);
    const int wcol = (wave & 1) * 64;
    const int tileM = blockIdx.y * BM;
    const int tileN = blockIdx.x * 128;
    const int fr  = lane & 15;
    const int fks = (lane >> 4) * 8;
    const int l4  = lane >> 2;        // row within 16-row chunk
    const int lm4 = lane & 3;         // 16B slot within 64B row
    f32x4 acc[RI][4] = {};

    for (int kb = 0; kb < K; kb += BK) {
        __syncthreads();
        #pragma unroll
        for (int i = 0; i < BM / 64; ++i) {
            int chunk = wave * (BM / 64) + i;
            const ushort* g = A + (size_t)(tileM + chunk * 16 + l4) * K + kb + lm4 * 8;
            __builtin_amdgcn_global_load_lds(
                (const __attribute__((address_space(1))) unsigned*)g,
                (__attribute__((address_space(3))) unsigned*)&lsa[chunk * 512], 16, 0, 0);
        }
        #pragma unroll
        for (int i = 0; i < 2; ++i) {
            int chunk = wave * 2 + i;
            const ushort* g = Bm + (size_t)(tileN + chunk * 16 + l4) * K + kb + lm4 * 8;
            __builtin_amdgcn_global_load_lds(
                (const __attribute__((address_space(1))) unsigned*)g,
                (__attribute__((address_space(3))) unsigned*)&lsb[chunk * 512], 16, 0, 0);
        }
        __syncthreads();
        short8_t af[RI], bfg[4];
        #pragma unroll
        for (int r = 0; r < RI; ++r)
            af[r] = *reinterpret_cast<const short8_t*>(&lsa[(wrow + r * 16 + fr) * BK + fks]);
        #pragma unroll
        for (int c = 0; c < 4; ++c)
            bfg[c] = *reinterpret_cast<const short8_t*>(&lsb[(wcol + c * 16 + fr) * BK + fks]);
        #pragma unroll
        for (int r = 0; r < RI; ++r)
            #pragma unroll
            for (int c = 0; c < 4; ++c)
                acc[r][c] = __builtin_amdgcn_mfma_f32_16x16x32_bf16(af[r], bfg[c], acc[r][c], 0, 0, 0);
    }

    const int rr = (lane >> 4) * 4;
    #pragma unroll
    for (int r = 0; r < RI; ++r) {
        #pragma unroll
        for (int c = 0; c < 4; ++c) {
            int n = tileN + wcol + c * 16 + fr;
            float bv = bias[n];
            #pragma unroll
            for (int q = 0; q < 4; ++q) {
                int m = tileM + wrow + r * 16 + rr + q;
                float v = (acc[r][c][q] + bv) * scale;
                if (OUT_F32) ((float*)Cout)[(size_t)m * N + n] = v;
                else         ((ushort*)Cout)[(size_t)m * N + n] = f2bf(v);
            }
        }
    }
}

__global__ __launch_bounds__(256) void gemm_qkv_kernel(
    const ushort* __restrict__ xb,
    const ushort* __restrict__ wq, const ushort* __restrict__ wk, const ushort* __restrict__ wv,
    const float* __restrict__ bq, const float* __restrict__ bk, const float* __restrict__ bv,
    ushort* __restrict__ Qb, ushort* __restrict__ Kb, ushort* __restrict__ Vb, float qscale)
{
    const ushort* Bm; const float* bias; ushort* out; float sc;
    if (blockIdx.z == 0)      { Bm = wq; bias = bq; out = Qb; sc = qscale; }
    else if (blockIdx.z == 1) { Bm = wk; bias = bk; out = Kb; sc = 1.0f; }
    else                      { Bm = wv; bias = bv; out = Vb; sc = 1.0f; }
    gemm_body<128, 0>(xb, Bm, bias, out, DD, DD, sc);
}

__global__ __launch_bounds__(256) void gemm_out_kernel(
    const ushort* __restrict__ ctxb, const ushort* __restrict__ wo,
    const float* __restrict__ bo, float* __restrict__ out)
{
    gemm_body<64, 1>(ctxb, wo, bo, out, DD, DD, 1.0f);
}

// ---------------- E tables: E_t[bh,j] = exp(c_t*ph_t*pf[h]*rk[bh,j]) for t=1,3 ----------------
__global__ __launch_bounds__(256) void tables_kernel(const ushort* __restrict__ Kb,
                                                     const float* __restrict__ pf,
                                                     float* __restrict__ E1, float* __restrict__ E3,
                                                     float a1, float a3) {
    int idx = blockIdx.x * blockDim.x + threadIdx.x;  // [0, BH*SS)
    int j  = idx & (SS - 1);
    int bh = idx >> 10;
    int b = bh >> 4, h = bh & 15;
    const ushort* kr = Kb + (size_t)(b * SS + j) * DD + h * HD;
    float s = 0.f;
    #pragma unroll
    for (int c = 0; c < HD; c += 8) {
        short8_t v = *reinterpret_cast<const short8_t*>(kr + c);
        #pragma unroll
        for (int e = 0; e < 8; ++e) s += bf2f((ushort)v[e]);
    }
    float ph = pf[h];
    E1[idx] = __expf(a1 * ph * s);
    E3[idx] = __expf(a3 * ph * s);
}

// ---------------- V transpose: Vt[b,h,d,j] = V[b,j,h*64+d] ----------------
__global__ __launch_bounds__(256) void transpose_v_kernel(const ushort* __restrict__ Vb,
                                                          ushort* __restrict__ Vt) {
    __shared__ ushort t[64][72];
    int bh = blockIdx.x; int b = bh >> 4, h = bh & 15;
    int j0 = blockIdx.y * 64;
    #pragma unroll
    for (int s = 0; s < 2; ++s) {
        int ch = threadIdx.x + s * 256;
        int row = ch >> 3, c = (ch & 7) * 8;
        *reinterpret_cast<short8_t*>(&t[row][c]) =
            *reinterpret_cast<const short8_t*>(Vb + (size_t)(b * SS + j0 + row) * DD + h * HD + c);
    }
    __syncthreads();
    #pragma unroll
    for (int s = 0; s < 2; ++s) {
        int ch = threadIdx.x + s * 256;
        int drow = ch >> 3, c = (ch & 7) * 8;
        short8_t v;
        #pragma unroll
        for (int e = 0; e < 8; ++e) v[e] = (short)t[c + e][drow];
        *reinterpret_cast<short8_t*>(Vt + (size_t)(bh * HD + drow) * SS + j0 + c) = v;
    }
}

// ---------------- single-pass resonance attention (round-2 structure) ----------------
// Q pre-scaled so QK^T gives S' = 0.025*log2e*S. p_t = y^(4+t)*E_t[j], y=exp2(S').
// E loads hoisted before QK^T (off the critical chain); no scheduling walls;
// NO restrictive launch_bounds min-waves (spill trap: VGPR+AGPR unified budget).
__global__ __launch_bounds__(256, 2) void attn_kernel(
    const ushort* __restrict__ Qb, const ushort* __restrict__ Kb,
    const ushort* __restrict__ Vt, const float* __restrict__ E1,
    const float* __restrict__ E3, ushort* __restrict__ ctxb)
{
    __shared__ float ybuf[4][16][68];   // per-wave y transpose; reused as ctx partials
    __shared__ float lbuf[4][4][16];    // [wave][t][row]
    const int wg  = blockIdx.x;
    const int swz = (wg & 7) * 256 + (wg >> 3);   // XCD swizzle (2048 % 8 == 0)
    const int bh  = swz >> 6;
    const int qt  = swz & 63;
    const int b = bh >> 4, h = bh & 15;
    const int wave = threadIdx.x >> 6;
    const int lane = threadIdx.x & 63;
    const int fr = lane & 15;
    const int g  = lane >> 4;
    const int fk = g * 8;

    const float wt[4] = {0.008f, 0.032f, 0.16f, 0.8f};   // momentum-collapsed weights

    // Q A-fragments (pre-scaled), 16 rows per block
    const ushort* qbase = Qb + (size_t)(b * SS + qt * 16 + fr) * DD + h * HD;
    const short8_t aq0 = *reinterpret_cast<const short8_t*>(qbase + fk);
    const short8_t aq1 = *reinterpret_cast<const short8_t*>(qbase + 32 + fk);

    f32x4 cacc[4][4] = {};   // [t][n2]  PV accumulators
    float l[4] = {0.f, 0.f, 0.f, 0.f};

    const float* e1h = E1 + bh * SS;
    const float* e3h = E3 + bh * SS;

    for (int it = 0; it < 4; ++it) {
        const int k0 = wave * 256 + it * 64;

        // ---- E factors loaded FIRST (independent of MFMA chain; latency hidden) ----
        const float* e1p = e1h + k0 + fk;
        const float* e3p = e3h + k0 + fk;
        float e1v[16], e3v[16];
        {
            float4 a = *reinterpret_cast<const float4*>(e1p);
            float4 bq_ = *reinterpret_cast<const float4*>(e1p + 4);
            float4 c = *reinterpret_cast<const float4*>(e1p + 32);
            float4 d = *reinterpret_cast<const float4*>(e1p + 36);
            e1v[0]=a.x; e1v[1]=a.y; e1v[2]=a.z; e1v[3]=a.w;
            e1v[4]=bq_.x; e1v[5]=bq_.y; e1v[6]=bq_.z; e1v[7]=bq_.w;
            e1v[8]=c.x; e1v[9]=c.y; e1v[10]=c.z; e1v[11]=c.w;
            e1v[12]=d.x; e1v[13]=d.y; e1v[14]=d.z; e1v[15]=d.w;
            a = *reinterpret_cast<const float4*>(e3p);
            bq_ = *reinterpret_cast<const float4*>(e3p + 4);
            c = *reinterpret_cast<const float4*>(e3p + 32);
            d = *reinterpret_cast<const float4*>(e3p + 36);
            e3v[0]=a.x; e3v[1]=a.y; e3v[2]=a.z; e3v[3]=a.w;
            e3v[4]=bq_.x; e3v[5]=bq_.y; e3v[6]=bq_.z; e3v[7]=bq_.w;
            e3v[8]=c.x; e3v[9]=c.y; e3v[10]=c.z; e3v[11]=c.w;
            e3v[12]=d.x; e3v[13]=d.y; e3v[14]=d.z; e3v[15]=d.w;
        }

        // ---- QK^T for this 16x64 tile ----
        f32x4 accn[4];
        #pragma unroll
        for (int n = 0; n < 4; ++n) {
            const ushort* kbase = Kb + (size_t)(b * SS + k0 + n * 16 + fr) * DD + h * HD;
            short8_t bk0 = *reinterpret_cast<const short8_t*>(kbase + fk);
            short8_t bk1 = *reinterpret_cast<const short8_t*>(kbase + 32 + fk);
            f32x4 z = {0.f, 0.f, 0.f, 0.f};
            z = __builtin_amdgcn_mfma_f32_16x16x32_bf16(aq0, bk0, z, 0, 0, 0);
            z = __builtin_amdgcn_mfma_f32_16x16x32_bf16(aq1, bk1, z, 0, 0, 0);
            accn[n] = z;
        }
        // ---- y = exp2(S') written to LDS in C-layout ----
        #pragma unroll
        for (int n = 0; n < 4; ++n)
            #pragma unroll
            for (int r = 0; r < 4; ++r)
                ybuf[wave][g * 4 + r][n * 16 + fr] = EXP2(accn[n][r]);

        // ---- read back in A-frag layout (compiler tracks DS dependence; same-wave DS in-order) ----
        f32x4 ya0 = *reinterpret_cast<f32x4*>(&ybuf[wave][fr][fk]);
        f32x4 ya1 = *reinterpret_cast<f32x4*>(&ybuf[wave][fr][fk + 4]);
        f32x4 ya2 = *reinterpret_cast<f32x4*>(&ybuf[wave][fr][32 + fk]);
        f32x4 ya3 = *reinterpret_cast<f32x4*>(&ybuf[wave][fr][36 + fk]);
        float yv[16];
        #pragma unroll
        for (int e = 0; e < 4; ++e) {
            yv[e] = ya0[e]; yv[4 + e] = ya1[e]; yv[8 + e] = ya2[e]; yv[12 + e] = ya3[e];
        }

        // ---- powers, l accumulation, bf16 pack ----
        float p0[16], p1[16], p2[16], p3[16];
        #pragma unroll
        for (int e = 0; e < 16; ++e) {
            float y  = yv[e];
            float y2 = y * y;
            float y4 = y2 * y2;
            float y5 = y4 * y;
            float y6 = y4 * y2;
            float y7 = y6 * y;
            p0[e] = y4;
            p1[e] = y5 * e1v[e];
            p2[e] = y6;
            p3[e] = y7 * e3v[e];
            l[0] += p0[e]; l[1] += p1[e]; l[2] += p2[e]; l[3] += p3[e];
        }
        union Frag { short8_t s; unsigned u[4]; };
        Frag pa0[4], pa1[4];
        #pragma unroll
        for (int i = 0; i < 4; ++i) {
            pa0[0].u[i] = pkbf(p0[2*i], p0[2*i+1]);
            pa0[1].u[i] = pkbf(p1[2*i], p1[2*i+1]);
            pa0[2].u[i] = pkbf(p2[2*i], p2[2*i+1]);
            pa0[3].u[i] = pkbf(p3[2*i], p3[2*i+1]);
            pa1[0].u[i] = pkbf(p0[8+2*i], p0[8+2*i+1]);
            pa1[1].u[i] = pkbf(p1[8+2*i], p1[8+2*i+1]);
            pa1[2].u[i] = pkbf(p2[8+2*i], p2[8+2*i+1]);
            pa1[3].u[i] = pkbf(p3[8+2*i], p3[8+2*i+1]);
        }
        // ---- PV: 4 accumulator sets ----
        #pragma unroll
        for (int n2 = 0; n2 < 4; ++n2) {
            const ushort* vb = Vt + (size_t)(bh * HD + n2 * 16 + fr) * SS + k0;
            short8_t v0 = *reinterpret_cast<const short8_t*>(vb + fk);
            short8_t v1 = *reinterpret_cast<const short8_t*>(vb + 32 + fk);
            #pragma unroll
            for (int t = 0; t < 4; ++t) {
                cacc[t][n2] = __builtin_amdgcn_mfma_f32_16x16x32_bf16(pa0[t].s, v0, cacc[t][n2], 0, 0, 0);
                cacc[t][n2] = __builtin_amdgcn_mfma_f32_16x16x32_bf16(pa1[t].s, v1, cacc[t][n2], 0, 0, 0);
            }
        }
    }

    // ---- epilogue: reduce l (intra-wave over fk-groups, then cross-wave) ----
    #pragma unroll
    for (int t = 0; t < 4; ++t) {
        float lt = l[t];
        lt += __shfl_xor(lt, 16);
        lt += __shfl_xor(lt, 32);
        if (lane < 16) lbuf[wave][t][lane] = lt;
    }
    __syncthreads();
    float wlf[4];
    #pragma unroll
    for (int t = 0; t < 4; ++t) {
        float s = lbuf[0][t][fr] + lbuf[1][t][fr] + lbuf[2][t][fr] + lbuf[3][t][fr];
        wlf[t] = wt[t] / s;
    }
    // per-lane rows are g*4+q; fetch wl for those rows
    float wls[4][4];
    #pragma unroll
    for (int t = 0; t < 4; ++t)
        #pragma unroll
        for (int q = 0; q < 4; ++q)
            wls[t][q] = __shfl(wlf[t], g * 4 + q);

    // combine t in-register, write per-wave partial ctx into (reused) ybuf
    #pragma unroll
    for (int n2 = 0; n2 < 4; ++n2) {
        #pragma unroll
        for (int q = 0; q < 4; ++q) {
            float v = wls[0][q] * cacc[0][n2][q] + wls[1][q] * cacc[1][n2][q]
                    + wls[2][q] * cacc[2][n2][q] + wls[3][q] * cacc[3][n2][q];
            ybuf[wave][g * 4 + q][n2 * 16 + fr] = v;
        }
    }
    __syncthreads();

    // final: sum 4 wave partials, write bf16 ctx
    const int row = threadIdx.x >> 4;
    const int d0  = (threadIdx.x & 15) * 4;
    float4 s0 = *reinterpret_cast<float4*>(&ybuf[0][row][d0]);
    float4 s1 = *reinterpret_cast<float4*>(&ybuf[1][row][d0]);
    float4 s2 = *reinterpret_cast<float4*>(&ybuf[2][row][d0]);
    float4 s3 = *reinterpret_cast<float4*>(&ybuf[3][row][d0]);
    float ox = s0.x + s1.x + s2.x + s3.x;
    float oy = s0.y + s1.y + s2.y + s3.y;
    float oz = s0.z + s1.z + s2.z + s3.z;
    float ow = s0.w + s1.w + s2.w + s3.w;
    uint2 o;
    o.x = pkbf(ox, oy);
    o.y = pkbf(oz, ow);
    size_t off = (size_t)(b * SS + qt * 16 + row) * DD + h * HD + d0;
    *reinterpret_cast<uint2*>(ctxb + off) = o;
}

// ---------------- launch ----------------
extern "C" void kernel_launch(void* const* d_in, const int* in_sizes, int n_in,
                              void* d_out, int out_size, void* d_ws, size_t ws_size,
                              hipStream_t stream) {
    const float* x  = (const float*)d_in[0];
    const float* Wq = (const float*)d_in[1];
    const float* bq = (const float*)d_in[2];
    const float* Wk = (const float*)d_in[3];
    const float* bk = (const float*)d_in[4];
    const float* Wv = (const float*)d_in[5];
    const float* bv = (const float*)d_in[6];
    const float* Wo = (const float*)d_in[7];
    const float* bo = (const float*)d_in[8];
    // d_in[9] resonance_bias: per-head row-constant -> cancels in softmax
    const float* pf = (const float*)d_in[10];

    // workspace layout (~32.3 MB)
    ushort* xb   = (ushort*)d_ws;
    ushort* wqb  = xb  + (size_t)2 * 1024 * 1024;
    ushort* wkb  = wqb + (size_t)1024 * 1024;
    ushort* wvb  = wkb + (size_t)1024 * 1024;
    ushort* wob  = wvb + (size_t)1024 * 1024;
    ushort* Qb   = wob + (size_t)1024 * 1024;
    ushort* Kb   = Qb  + (size_t)2 * 1024 * 1024;
    ushort* Vb   = Kb  + (size_t)2 * 1024 * 1024;
    ushort* Vt   = Vb  + (size_t)2 * 1024 * 1024;
    ushort* ctxb = Vt  + (size_t)2 * 1024 * 1024;
    float*  E1p  = (float*)(ctxb + (size_t)2 * 1024 * 1024);
    float*  E3p  = E1p + (size_t)BH * SS;

    // per-iteration constants (match reference f32 casting)
    float ph[4], ctv[4];
    for (int t = 0; t < 4; ++t) {
        double tn = (double)t / 4.0;
        ph[t]  = sinf((float)(2.0 * tn * M_PI + 0.0));
        ctv[t] = (float)((0.8 + 0.2 * (double)t) * 0.125);  // beta_t / sqrt(HD)
    }
    const double LOG2E = 1.44269504088896340736;
    float qscale = (float)(0.025 * LOG2E);  // Q pre-scale: S' = 0.025*log2e*S
    float a1 = ctv[1] * ph[1];   // c1 * sin(pi/2)
    float a3 = ctv[3] * ph[3];   // c3 * sin(3pi/2)

    cvt_all_kernel<<<6144, 256, 0, stream>>>(x, Wq, Wk, Wv, Wo, xb, wqb, wkb, wvb, wob);

    gemm_qkv_kernel<<<dim3(8, 16, 3), 256, 0, stream>>>(xb, wqb, wkb, wvb, bq, bk, bv,
                                                        Qb, Kb, Vb, qscale);

    tables_kernel<<<BH * SS / 256, 256, 0, stream>>>(Kb, pf, E1p, E3p, a1, a3);
    transpose_v_kernel<<<dim3(BH, SS / 64), 256, 0, stream>>>(Vb, Vt);

    attn_kernel<<<2048, 256, 0, stream>>>(Qb, Kb, Vt, E1p, E3p, ctxb);

    gemm_out_kernel<<<dim3(8, 32), 256, 0, stream>>>(ctxb, wob, bo, (float*)d_out);
}